// Round 4
// baseline (336.309 us; speedup 1.0000x reference)
//
#include <hip/hip_runtime.h>
#include <hip/hip_bf16.h>
#include <stdint.h>

#define BB 32
#define GG 100
#define AA 8400
#define TPB 256
#define NCH 33                         // ceil(8400/256) chunks per image
#define TKB 256                        // kB block size (4 waves)
#define WPB 4                          // kB: one (b,g) item per wave
#define BA (BB*AA)
#define NG (BB*GG)
#define NBLK (BA/TPB)                  // 1050 kCD blocks

typedef __hip_bfloat16 bf16;

struct P {
  const void *outs, *labs, *ss;
  float4 *box4, *meta4, *gtb, *gtc;   // per-anchor box/meta; per-gt box/center
  float4 *cbox, *cmeta;               // per-image compacted fg anchors
  float *miou, *pb, *pf;              // per-block BCE / fg partials (no atomics)
  int *cnt, *gmax, *nfg, *chunkcnt, *ticket;
  float *out;
};

// runtime input-dtype detection: strides[0]==8.0
// f32 word 0x41000000 ; bf16 pair (8.0,8.0) 0x41004100
__device__ __forceinline__ int dtypeFlag(const void* ss){
  return (((const uint32_t*)ss)[0] == 0x41000000u) ? 1 : 0;
}
__device__ __forceinline__ float ld(const void* p, int i, int isf32){
  return isf32 ? ((const float*)p)[i] : __bfloat162float(((const bf16*)p)[i]);
}
// analytic anchor geometry (exact: ints + pow2 strides exact in f32/bf16)
__device__ __forceinline__ void ageom(int a, float& xc, float& yc, float& r){
  int x, y, s;
  if (a < 6400){ x = a % 80; y = a / 80; s = 8; }
  else if (a < 8000){ int q = a - 6400; x = q % 40; y = q / 40; s = 16; }
  else { int q = a - 8000; x = q % 20; y = q / 20; s = 32; }
  float fs = (float)s;
  xc = ((float)x + 0.5f) * fs;
  yc = ((float)y + 0.5f) * fs;
  r  = 2.5f * fs;
}
__device__ __forceinline__ uint32_t apack(int a){
  int x, y, s;
  if (a < 6400){ x = a % 80; y = a / 80; s = 8; }
  else if (a < 8000){ int q = a - 6400; x = q % 40; y = q / 40; s = 16; }
  else { int q = a - 8000; x = q % 20; y = q / 20; s = 32; }
  uint32_t ix = (uint32_t)(x*s + s/2), iy = (uint32_t)(y*s + s/2);
  return ix | (iy << 16);
}

// ---- kA: gt structs (self-computed) + per-anchor staging + fg + chunk count
__global__ __launch_bounds__(TPB) void kA(P p){
  __shared__ float4 s_gtb[GG], s_gtc[GG];
  __shared__ float s_o[TPB*6];
  __shared__ int s_w[4];
  __shared__ int s_ng;
  int t = threadIdx.x;
  int c = blockIdx.x, b = blockIdx.y;
  int isf = dtypeFlag(p.ss);
  if (t == 0) s_ng = 0;
  if (c == 0 && b == 0 && t == 0) *p.ticket = 0;   // for fused kCD finisher
  int nel = min(TPB*6, AA*6 - c*(TPB*6));      // floats in this chunk
  if (isf){
    const float4* src = (const float4*)((const float*)p.outs + (size_t)b*AA*6 + (size_t)c*(TPB*6));
    float4* dst = (float4*)s_o;
    for (int i = t; i < nel/4; i += TPB) dst[i] = src[i];
  } else {
    const uint4* src = (const uint4*)((const bf16*)p.outs + (size_t)b*AA*6 + (size_t)c*(TPB*6));
    for (int i = t; i < nel/8; i += TPB){
      uint4 u = src[i];
      int o = i*8;
      s_o[o+0]=__uint_as_float(u.x<<16); s_o[o+1]=__uint_as_float(u.x&0xffff0000u);
      s_o[o+2]=__uint_as_float(u.y<<16); s_o[o+3]=__uint_as_float(u.y&0xffff0000u);
      s_o[o+4]=__uint_as_float(u.z<<16); s_o[o+5]=__uint_as_float(u.z&0xffff0000u);
      s_o[o+6]=__uint_as_float(u.w<<16); s_o[o+7]=__uint_as_float(u.w&0xffff0000u);
    }
  }
  __syncthreads();
  if (t < GG){
    int i = b*GG + t;
    float l0 = ld(p.labs, i*5  , isf);
    float gcx= ld(p.labs, i*5+1, isf);
    float gcy= ld(p.labs, i*5+2, isf);
    float gw = ld(p.labs, i*5+3, isf);
    float gh = ld(p.labs, i*5+4, isf);
    int valid = (l0+gcx+gcy+gw+gh) > 0.f;
    float4 vb = make_float4(gcx-gw*0.5f, gcy-gh*0.5f, gcx+gw*0.5f, gcy+gh*0.5f);
    float4 vc = make_float4(gcx, gcy, gw*gh, valid ? 1.f : 0.f);
    s_gtb[t] = vb; s_gtc[t] = vc;
    if (c == 0){ p.gtb[i] = vb; p.gtc[i] = vc; }
    if (valid) atomicMax(&s_ng, t+1);
  }
  __syncthreads();
  int ng = s_ng;
  if (c == 0 && t == 0) p.gmax[b] = ng;
  int a = c*TPB + t;
  int fg = 0;
  if (a < AA){
    float cx=s_o[t*6], cy=s_o[t*6+1], w=s_o[t*6+2], h=s_o[t*6+3], ob=s_o[t*6+4], cl=s_o[t*6+5];
    int idx = b*AA + a;
    p.box4[idx] = make_float4(cx-w*0.5f, cy-h*0.5f, cx+w*0.5f, cy+h*0.5f);
    float so = 1.f/(1.f+expf(-ob));
    float sc = 1.f/(1.f+expf(-cl));
    float pcc = -logf(sqrtf(sc*so) + 1e-9f);
    float xc, yc, r; ageom(a, xc, yc, r);
    for (int g = 0; g < ng; ++g){
      float4 gb = s_gtb[g], gc = s_gtc[g];
      bool inb = (xc>gb.x)&&(xc<gb.z)&&(yc>gb.y)&&(yc<gb.w);
      bool inc = (fabsf(xc-gc.x)<r)&&(fabsf(yc-gc.y)<r);
      fg |= (gc.w != 0.f) && (inb||inc);
    }
    p.meta4[idx] = make_float4(w*h, pcc, fg ? 1.f : 0.f, cl);
    p.cnt[idx] = 0;
  }
  int lane = t & 63, wid = t >> 6;
  unsigned long long m = __ballot(fg);
  if (lane == 0) s_w[wid] = __popcll(m);
  __syncthreads();
  if (t == 0) p.chunkcnt[b*NCH + c] = s_w[0]+s_w[1]+s_w[2]+s_w[3];
}

// ---- kE: parallel order-preserving fg compaction (one block per chunk) -----
__global__ __launch_bounds__(TPB) void kE(P p){
  __shared__ int s_off;
  __shared__ int s_w[4];
  int t = threadIdx.x, c = blockIdx.x, b = blockIdx.y;
  int lane = t & 63, wid = t >> 6;
  if (wid == 0){
    int v = (lane < c) ? p.chunkcnt[b*NCH + lane] : 0;   // c <= 32 < 64 lanes
#pragma unroll
    for (int off=32; off; off>>=1) v += __shfl_xor(v, off);
    if (lane == 0) s_off = v;
  }
  int a = c*TPB + t;
  float4 mt = make_float4(0,0,0,0);
  int fg = 0;
  if (a < AA){ mt = p.meta4[b*AA+a]; fg = (mt.z != 0.f) ? 1 : 0; }
  unsigned long long m = __ballot(fg);
  int rank = __popcll(m & ((1ull<<lane)-1ull));
  if (lane == 0) s_w[wid] = __popcll(m);
  __syncthreads();
  int off = s_off;
  for (int w2 = 0; w2 < wid; ++w2) off += s_w[w2];
  if (fg){
    int pos = off + rank;
    p.cbox [b*AA+pos] = p.box4[b*AA+a];
    // cmeta: (area, pcc, a, packed int centers)
    p.cmeta[b*AA+pos] = make_float4(mt.x, mt.y, __int_as_float(a),
                                    __uint_as_float(apack(a)));
  }
  if (c == NCH-1 && t == 0)
    p.nfg[b] = s_off + s_w[0]+s_w[1]+s_w[2]+s_w[3];
}

// ---- kB: per-(b,g) dyn_k + selection -------------------------------------
// v5: streaming order-statistics, ONE WAVE per (b,g). r2/r3 post-mortem: any
// 17-slot per-thread array gets spilled (WRITE_SIZE 4.0/2.1MB) regardless of
// launch_bounds. But kB only needs two mergeable 10-element summaries:
//   (a) top-10 ious (values, summed descending)  -> dyn_k
//   (b) bottom-10 (cost,pos) in lex order        -> the selected anchors
// Each thread streams its strided anchors ONCE keeping sorted 10-element
// insertion lists in registers (fixed size, fully unrolled -> static indices,
// no scratch). Wave-merge = repeated argmax/argmin over list HEADS (shuffles
// only; consuming a head is a static 9-shift). No LDS slots, no barriers,
// no rescans, no block-wide coordination at all.
// Exactness: global top-10 of a union == top-10 of union of per-thread
// top-10s (multiset property); value ties don't change the descending sum
// (same accumulation order v0 validated, bit-exact dk). (cost,pos) is a
// strict total order (pos unique, == original anchor order == jnp stable
// argsort tiebreak) -> identical selected set and order.
__global__ __launch_bounds__(TKB) void kB(P p){
  int lane = threadIdx.x & 63, wid = threadIdx.x >> 6;
  int item = blockIdx.x*WPB + wid;          // 3200 items, balanced across XCDs
  int b = item / GG, g = item - b*GG;
  float4 gc = p.gtc[b*GG+g];
  if (gc.w == 0.f) return;                  // dead gt: whole wave exits
  float4 gb = p.gtb[b*GG+g];
  float glx=gb.x, gly=gb.y, ghx=gb.z, ghy=gb.w, gcx=gc.x, gcy=gc.y, ga=gc.z;
  int base = b*AA;
  int nfg = p.nfg[b];

  float il[10];                             // top-10 iou, descending
  float cl[10]; int pl[10];                 // bottom-10 (cost,pos), ascending
#pragma unroll
  for (int k=0;k<10;k++){ il[k] = -1.f; cl[k] = 3.0e38f; pl[k] = 0x7fffffff; }

  int nit = (nfg + 63) >> 6;
  for (int it=0; it<nit; ++it){
    int pos = (it<<6) + lane;
    if (pos < nfg){
      float4 mt = p.cmeta[base+pos];
      float4 bx = p.cbox [base+pos];
      float tlx=fmaxf(glx,bx.x), tly=fmaxf(gly,bx.y);
      float brx=fminf(ghx,bx.z), bry=fminf(ghy,bx.w);
      float iw=fmaxf(brx-tlx,0.f), ih=fmaxf(bry-tly,0.f);
      float inter=iw*ih;
      float v = inter/(ga + mt.x - inter + 1e-12f);
      // top-10 iou insert (values only; equal-tail drops are sum-neutral)
      if (v > il[9]){
        il[9] = v;
#pragma unroll
        for (int k=9;k>0;--k) if (il[k] > il[k-1]){
          float tm=il[k-1]; il[k-1]=il[k]; il[k]=tm;
        }
      }
      // cost (identical formula/order to v0 phase 2; same iou value bit-exact)
      uint32_t u = __float_as_uint(mt.w);
      float xc = (float)(u & 0xffffu), yc = (float)(u >> 16);
      int a = __float_as_int(mt.z);
      float r = (a < 6400) ? 20.f : ((a < 8000) ? 40.f : 80.f);
      bool inb=(xc>glx)&&(xc<ghx)&&(yc>gly)&&(yc<ghy);
      bool inc=(fabsf(xc-gcx)<r)&&(fabsf(yc-gcy)<r);
      float cst = mt.y + 3.f*(-logf(v+1e-8f)) + ((inb&&inc)?0.f:100000.f);
      // bottom-10 (cost,pos) lex insert
      if (cst < cl[9] || (cst == cl[9] && pos < pl[9])){
        cl[9]=cst; pl[9]=pos;
#pragma unroll
        for (int k=9;k>0;--k){
          bool sw = (cl[k] < cl[k-1]) || (cl[k]==cl[k-1] && pl[k] < pl[k-1]);
          if (sw){
            float tc=cl[k-1]; cl[k-1]=cl[k]; cl[k]=tc;
            int   tp=pl[k-1]; pl[k-1]=pl[k]; pl[k]=tp;
          }
        }
      }
    }
  }

  // dk: merge 64 sorted desc lists via heads -> global top-10 descending sum
  float sum = 0.f;
  for (int k=0;k<10;k++){
    float gv = il[0];
#pragma unroll
    for (int off=32; off; off>>=1) gv = fmaxf(gv, __shfl_xor(gv, off));
    if (gv <= 0.f) break;                   // wave-uniform (post-reduce)
    sum += gv;
    unsigned long long ms = __ballot(il[0] == gv);
    if ((int)(__ffsll(ms)-1) == lane){      // one consumer: static shift-up
#pragma unroll
      for (int k2=0;k2<9;k2++) il[k2]=il[k2+1];
      il[9] = -1.f;
    }
  }
  int dk = (int)sum; if (dk<1) dk=1; if (dk>10) dk=10;

  // selection: merge 64 sorted asc lists -> dk global smallest (cost,pos)
  int mysel = -1;
  for (int k=0;k<dk;k++){
    float gv = cl[0]; int gi = pl[0];
#pragma unroll
    for (int off=32; off; off>>=1){
      float ov=__shfl_xor(gv,off); int oi=__shfl_xor(gi,off);
      if (ov<gv || (ov==gv && oi<gi)){ gv=ov; gi=oi; }
    }
    if (gv >= 2.9e38f) break;               // candidates exhausted (uniform)
    if (lane == k) mysel = gi;              // k-th selection -> lane k
    if (cl[0]==gv && pl[0]==gi){            // unique owner (pos unique)
#pragma unroll
      for (int k2=0;k2<9;k2++){ cl[k2]=cl[k2+1]; pl[k2]=pl[k2+1]; }
      cl[9]=3.0e38f; pl[9]=0x7fffffff;
    }
  }

  if (mysel >= 0){                          // lanes 0..dk-1 hold selections
    int pos = mysel;
    float4 mt = p.cmeta[base+pos];
    float4 bx = p.cbox [base+pos];
    int a = __float_as_int(mt.z);
    float tlx=fmaxf(glx,bx.x), tly=fmaxf(gly,bx.y);
    float brx=fminf(ghx,bx.z), bry=fminf(ghy,bx.w);
    float iw=fmaxf(brx-tlx,0.f), ih=fmaxf(bry-tly,0.f);
    float inter=iw*ih;
    float iou=inter/(ga + mt.x - inter + 1e-12f);
    atomicAdd(&p.cnt[base+a], 1);
    p.miou[base+a] = iou;                   // races only when cnt>1; kCD recomputes
  }
}

// ---- kCD: conflict resolution + masked BCE + fused finalize ---------------
// kD fused via last-arriving-block ticket (saves one launch + gap).
// Finisher replicates kD's exact summation order -> bit-identical output.
__global__ __launch_bounds__(TPB) void kCD(P p){
  int t = threadIdx.x;
  int idx = blockIdx.x*TPB + t;
  float bce=0.f, fgv=0.f;
  if (idx < BA){
    int cgt = p.cnt[idx];
    if (cgt > 0){
      int b = idx/AA, a = idx - b*AA;
      float4 mt = p.meta4[idx];
      float iouv;
      if (cgt == 1){ iouv = p.miou[idx]; }
      else {
        float4 bx = p.box4[idx];
        float xc,yc,r; ageom(a,xc,yc,r);
        int ng = p.gmax[b];
        float best=3.9e38f, biou=0.f;
        for (int g=0; g<ng; ++g){
          float4 gbb = p.gtb[b*GG+g], gcc = p.gtc[b*GG+g];
          float cost, iou = 0.f;
          if (gcc.w != 0.f){
            float tlx=fmaxf(gbb.x,bx.x), tly=fmaxf(gbb.y,bx.y);
            float brx=fminf(gbb.z,bx.z), bry=fminf(gbb.w,bx.w);
            float iw=fmaxf(brx-tlx,0.f), ih=fmaxf(bry-tly,0.f);
            float inter=iw*ih;
            iou = inter/(gcc.z + mt.x - inter + 1e-12f);
            bool inb=(xc>gbb.x)&&(xc<gbb.z)&&(yc>gbb.y)&&(yc<gbb.w);
            bool inc=(fabsf(xc-gcc.x)<r)&&(fabsf(yc-gcc.y)<r);
            cost = mt.y + 3.f*(-logf(iou+1e-8f)) + ((inb&&inc)?0.f:100000.f);
          } else cost = 1e9f;
          if (cost < best){ best=cost; biou=iou; }   // first-index argmin
        }
        iouv = biou;
      }
      float z = mt.w;
      float e = expf(-fabsf(z));
      float spz = fmaxf(z,0.f)+log1pf(e);
      float spn = fmaxf(-z,0.f)+log1pf(e);
      bce = iouv*spn + (1.f-iouv)*spz;
      fgv = 1.f;
    }
  }
  for (int off=32; off; off>>=1){
    bce += __shfl_xor(bce, off);
    fgv += __shfl_xor(fgv, off);
  }
  __shared__ float s_b[4], s_f[4];
  __shared__ int s_last;
  int lane = t & 63, wid = t >> 6;
  if (lane==0){ s_b[wid]=bce; s_f[wid]=fgv; }
  __syncthreads();
  if (t==0){
    // disjoint per-block partials: no cross-block atomics on the data path
    p.pb[blockIdx.x] = s_b[0]+s_b[1]+s_b[2]+s_b[3];
    p.pf[blockIdx.x] = s_f[0]+s_f[1]+s_f[2]+s_f[3];
    __threadfence();                       // publish partials (device scope)
    int old = atomicAdd(p.ticket, 1);
    s_last = (old == NBLK-1) ? 1 : 0;
  }
  __syncthreads();
  if (s_last){
    __threadfence();                       // acquire all partials
    float sb=0.f, sf=0.f;
    for (int i = t; i < NBLK; i += TPB){ sb += p.pb[i]; sf += p.pf[i]; }
#pragma unroll
    for (int off=32; off; off>>=1){
      sb += __shfl_xor(sb, off);
      sf += __shfl_xor(sf, off);
    }
    __syncthreads();                       // s_b/s_f reuse fence
    if (lane==0){ s_b[wid]=sb; s_f[wid]=sf; }
    __syncthreads();
    if (t==0){
      float tb=s_b[0]+s_b[1]+s_b[2]+s_b[3];
      float tf=s_f[0]+s_f[1]+s_f[2]+s_f[3];
      p.out[0] = tb / fmaxf(tf, 1.f);
    }
  }
}

extern "C" void kernel_launch(void* const* d_in, const int* in_sizes, int n_in,
                              void* d_out, int out_size, void* d_ws, size_t ws_size,
                              hipStream_t stream) {
  P p;
  p.outs = d_in[0];
  p.labs = d_in[1];
  p.ss   = d_in[4];
  char* w = (char*)d_ws;
  p.box4  = (float4*)w; w += (size_t)BA*sizeof(float4);
  p.meta4 = (float4*)w; w += (size_t)BA*sizeof(float4);
  p.cbox  = (float4*)w; w += (size_t)BA*sizeof(float4);
  p.cmeta = (float4*)w; w += (size_t)BA*sizeof(float4);
  p.gtb   = (float4*)w; w += (size_t)NG*sizeof(float4);
  p.gtc   = (float4*)w; w += (size_t)NG*sizeof(float4);
  p.miou  = (float*)w;  w += (size_t)BA*sizeof(float);
  p.cnt   = (int*)w;    w += (size_t)BA*sizeof(int);
  p.gmax  = (int*)w;    w += (size_t)BB*sizeof(int);
  p.nfg   = (int*)w;    w += (size_t)BB*sizeof(int);
  p.chunkcnt = (int*)w; w += (size_t)BB*NCH*sizeof(int);
  p.pb    = (float*)w;  w += (size_t)NBLK*sizeof(float);
  p.pf    = (float*)w;  w += (size_t)NBLK*sizeof(float);
  p.ticket= (int*)w;    w += sizeof(int);
  p.out   = (float*)d_out;

  kA<<<dim3(NCH, BB), TPB, 0, stream>>>(p);
  kE<<<dim3(NCH, BB), TPB, 0, stream>>>(p);
  kB<<<(BB*GG)/WPB, TKB, 0, stream>>>(p);
  kCD<<<NBLK, TPB, 0, stream>>>(p);
}

// Round 5
// 211.494 us; speedup vs baseline: 1.5902x; 1.5902x over previous
//
#include <hip/hip_runtime.h>
#include <hip/hip_bf16.h>
#include <stdint.h>

#define BB 32
#define GG 100
#define AA 8400
#define TPB 256
#define NCH 33                         // ceil(8400/256) chunks per image
#define TKB 512                        // kB block size (8 waves)
#define BA (BB*AA)
#define NG (BB*GG)
#define NBLK (BA/TPB)                  // 1050 kCD blocks
#define PCAP 8416                      // positives cap (>= AA, cannot overflow)
#define GCAP 128                       // geo cap (provably <= 75 per gt)

typedef __hip_bfloat16 bf16;

struct P {
  const void *outs, *labs, *ss;
  float4 *box4, *meta4, *gtb, *gtc;   // per-anchor box/meta; per-gt box/center
  float4 *cbox;                       // per-image compacted fg pred boxes
  uint32_t *cpk;                      // compacted packed (xc,yc,lvl)
  float *carea, *cpcc;                // compacted pred area / cls-cost
  float *miou, *pb, *pf;              // per-block BCE / fg partials
  int *cnt, *gmax, *nfg, *chunkcnt, *ticket;
  float *out;
};

// runtime input-dtype detection: strides[0]==8.0
// f32 word 0x41000000 ; bf16 pair (8.0,8.0) 0x41004100
__device__ __forceinline__ int dtypeFlag(const void* ss){
  return (((const uint32_t*)ss)[0] == 0x41000000u) ? 1 : 0;
}
__device__ __forceinline__ float ld(const void* p, int i, int isf32){
  return isf32 ? ((const float*)p)[i] : __bfloat162float(((const bf16*)p)[i]);
}
// analytic anchor geometry (exact: ints + pow2 strides exact in f32/bf16)
__device__ __forceinline__ void ageom(int a, float& xc, float& yc, float& r){
  int x, y, s;
  if (a < 6400){ x = a % 80; y = a / 80; s = 8; }
  else if (a < 8000){ int q = a - 6400; x = q % 40; y = q / 40; s = 16; }
  else { int q = a - 8000; x = q % 20; y = q / 20; s = 32; }
  float fs = (float)s;
  xc = ((float)x + 0.5f) * fs;
  yc = ((float)y + 0.5f) * fs;
  r  = 2.5f * fs;
}
// pack integer center + level: xc(10) | yc(10)<<10 | lvl<<20
__device__ __forceinline__ uint32_t apack2(int a){
  int x, y, s, lvl;
  if (a < 6400){ x = a % 80; y = a / 80; s = 8; lvl = 0; }
  else if (a < 8000){ int q = a - 6400; x = q % 40; y = q / 40; s = 16; lvl = 1; }
  else { int q = a - 8000; x = q % 20; y = q / 20; s = 32; lvl = 2; }
  return (uint32_t)(x*s + s/2) | ((uint32_t)(y*s + s/2) << 10) | ((uint32_t)lvl << 20);
}
// exact inverse: packed -> anchor id
__device__ __forceinline__ int adecode(uint32_t u){
  int xi = u & 1023, yi = (u >> 10) & 1023, lvl = (int)(u >> 20);
  int sh = 3 + lvl, hf = 4 << lvl;
  int ax = (xi - hf) >> sh, ay = (yi - hf) >> sh;
  if (lvl == 0) return ay*80 + ax;
  if (lvl == 1) return 6400 + ay*40 + ax;
  return 8000 + ay*20 + ax;
}

// ---- kA: gt structs (self-computed) + per-anchor staging + fg + chunk count
__global__ __launch_bounds__(TPB) void kA(P p){
  __shared__ float4 s_gtb[GG], s_gtc[GG];
  __shared__ float s_o[TPB*6];
  __shared__ int s_w[4];
  __shared__ int s_ng;
  int t = threadIdx.x;
  int c = blockIdx.x, b = blockIdx.y;
  int isf = dtypeFlag(p.ss);
  if (t == 0) s_ng = 0;
  if (c == 0 && b == 0 && t == 0) *p.ticket = 0;   // for fused kCD finisher
  int nel = min(TPB*6, AA*6 - c*(TPB*6));      // floats in this chunk
  if (isf){
    const float4* src = (const float4*)((const float*)p.outs + (size_t)b*AA*6 + (size_t)c*(TPB*6));
    float4* dst = (float4*)s_o;
    for (int i = t; i < nel/4; i += TPB) dst[i] = src[i];
  } else {
    const uint4* src = (const uint4*)((const bf16*)p.outs + (size_t)b*AA*6 + (size_t)c*(TPB*6));
    for (int i = t; i < nel/8; i += TPB){
      uint4 u = src[i];
      int o = i*8;
      s_o[o+0]=__uint_as_float(u.x<<16); s_o[o+1]=__uint_as_float(u.x&0xffff0000u);
      s_o[o+2]=__uint_as_float(u.y<<16); s_o[o+3]=__uint_as_float(u.y&0xffff0000u);
      s_o[o+4]=__uint_as_float(u.z<<16); s_o[o+5]=__uint_as_float(u.z&0xffff0000u);
      s_o[o+6]=__uint_as_float(u.w<<16); s_o[o+7]=__uint_as_float(u.w&0xffff0000u);
    }
  }
  __syncthreads();
  if (t < GG){
    int i = b*GG + t;
    float l0 = ld(p.labs, i*5  , isf);
    float gcx= ld(p.labs, i*5+1, isf);
    float gcy= ld(p.labs, i*5+2, isf);
    float gw = ld(p.labs, i*5+3, isf);
    float gh = ld(p.labs, i*5+4, isf);
    int valid = (l0+gcx+gcy+gw+gh) > 0.f;
    float4 vb = make_float4(gcx-gw*0.5f, gcy-gh*0.5f, gcx+gw*0.5f, gcy+gh*0.5f);
    float4 vc = make_float4(gcx, gcy, gw*gh, valid ? 1.f : 0.f);
    s_gtb[t] = vb; s_gtc[t] = vc;
    if (c == 0){ p.gtb[i] = vb; p.gtc[i] = vc; }
    if (valid) atomicMax(&s_ng, t+1);
  }
  __syncthreads();
  int ng = s_ng;
  if (c == 0 && t == 0) p.gmax[b] = ng;
  int a = c*TPB + t;
  int fg = 0;
  if (a < AA){
    float cx=s_o[t*6], cy=s_o[t*6+1], w=s_o[t*6+2], h=s_o[t*6+3], ob=s_o[t*6+4], cl=s_o[t*6+5];
    int idx = b*AA + a;
    p.box4[idx] = make_float4(cx-w*0.5f, cy-h*0.5f, cx+w*0.5f, cy+h*0.5f);
    float so = 1.f/(1.f+expf(-ob));
    float sc = 1.f/(1.f+expf(-cl));
    float pcc = -logf(sqrtf(sc*so) + 1e-9f);
    float xc, yc, r; ageom(a, xc, yc, r);
    for (int g = 0; g < ng; ++g){
      float4 gb = s_gtb[g], gc = s_gtc[g];
      bool inb = (xc>gb.x)&&(xc<gb.z)&&(yc>gb.y)&&(yc<gb.w);
      bool inc = (fabsf(xc-gc.x)<r)&&(fabsf(yc-gc.y)<r);
      fg |= (gc.w != 0.f) && (inb||inc);
    }
    p.meta4[idx] = make_float4(w*h, pcc, fg ? 1.f : 0.f, cl);
    p.cnt[idx] = 0;
  }
  int lane = t & 63, wid = t >> 6;
  unsigned long long m = __ballot(fg);
  if (lane == 0) s_w[wid] = __popcll(m);
  __syncthreads();
  if (t == 0) p.chunkcnt[b*NCH + c] = s_w[0]+s_w[1]+s_w[2]+s_w[3];
}

// ---- kE: parallel order-preserving fg compaction (one block per chunk) -----
__global__ __launch_bounds__(TPB) void kE(P p){
  __shared__ int s_off;
  __shared__ int s_w[4];
  int t = threadIdx.x, c = blockIdx.x, b = blockIdx.y;
  int lane = t & 63, wid = t >> 6;
  if (wid == 0){
    int v = (lane < c) ? p.chunkcnt[b*NCH + lane] : 0;   // c <= 32 < 64 lanes
#pragma unroll
    for (int off=32; off; off>>=1) v += __shfl_xor(v, off);
    if (lane == 0) s_off = v;
  }
  int a = c*TPB + t;
  float4 mt = make_float4(0,0,0,0);
  int fg = 0;
  if (a < AA){ mt = p.meta4[b*AA+a]; fg = (mt.z != 0.f) ? 1 : 0; }
  unsigned long long m = __ballot(fg);
  int rank = __popcll(m & ((1ull<<lane)-1ull));
  if (lane == 0) s_w[wid] = __popcll(m);
  __syncthreads();
  int off = s_off;
  for (int w2 = 0; w2 < wid; ++w2) off += s_w[w2];
  if (fg){
    int pos = off + rank;
    p.cbox [b*AA+pos] = p.box4[b*AA+a];
    p.cpk  [b*AA+pos] = apack2(a);
    p.carea[b*AA+pos] = mt.x;
    p.cpcc [b*AA+pos] = mt.y;
  }
  if (c == NCH-1 && t == 0)
    p.nfg[b] = s_off + s_w[0]+s_w[1]+s_w[2]+s_w[3];
}

// ---- kB: per-(b,g) dyn_k + selection -------------------------------------
// v6: COMPACT-THEN-SELECT. r4 post-mortem: one wave/item = 13% occupancy and
// per-pair sorted-insert bubbles (~every wave-iteration) -> 186us. But the
// candidate sets are tiny: only POSITIVE ious affect the top-10 sum (zeros
// are sum-neutral; positive requires pred-box/gt-box overlap, ~4% of pairs);
// and the bottom-dk is geo-only (geo cost <= ~76 < 100000 <= non-geo cost,
// strict separation; geo count provably <= 75: in_ctr window <= 5x5 per
// level x 3 levels). So: v0's 8-wave geometry, a lean ~30-op screen per
// pair, wave-aggregated push of survivors into small LDS lists, then wave 0
// alone selects from ~300 / <=75 entries (pop-style, no per-lane 10-arrays
// in any hot path -> VGPR stays low, no spill, no bubbles).
// Exactness: fp expressions verbatim from v0 (absmax 0 x4 rounds); top-10
// sum over positives == top-10 sum (x+0 exact); positives <= nfg <= 8400 so
// PCAP cannot overflow; rare gcnt<dk covered by exact k-th-smallest rescan.
__global__ __launch_bounds__(TKB) void kB(P p){
  __shared__ float s_pos[PCAP];
  __shared__ float s_gcost[GCAP];
  __shared__ int   s_gpos[GCAP];
  __shared__ int   s_pcnt, s_gcnt;
  int t = threadIdx.x;
  int lane = t & 63, wid = t >> 6;
  int item = blockIdx.x;
  int b = item / GG, g = item - b*GG;       // balanced across XCDs
  if (t == 0){ s_pcnt = 0; s_gcnt = 0; }
  float4 gc = p.gtc[b*GG+g];
  if (gc.w == 0.f) return;                  // uniform exit, pre-barrier
  float4 gb = p.gtb[b*GG+g];
  float glx=gb.x, gly=gb.y, ghx=gb.z, ghy=gb.w, gcx=gc.x, gcy=gc.y, ga=gc.z;
  int base = b*AA;
  int nfg = p.nfg[b];
  unsigned long long lmlt = (1ull<<lane) - 1ull;
  __syncthreads();                          // s_pcnt/s_gcnt init visible

  // main screen: ~30 VALU/pair, 20B/pair steady; heavy math only on hits
  int nIt = (nfg + TKB - 1) / TKB;
  for (int it = 0; it < nIt; ++it){
    int pos = it*TKB + t;
    bool vld = pos < nfg;
    bool ovl = false, geo = false;
    float v = 0.f, cst = 0.f;
    if (vld){
      uint32_t u = p.cpk[base+pos];
      float xc = (float)(u & 1023u), yc = (float)((u>>10)&1023u);
      float r  = (float)(20u << (u>>20));
      bool inb = (xc>glx)&&(xc<ghx)&&(yc>gly)&&(yc<ghy);
      geo = inb && (fabsf(xc-gcx)<r) && (fabsf(yc-gcy)<r);
      float4 bx = p.cbox[base+pos];
      float tlx=fmaxf(glx,bx.x), tly=fmaxf(gly,bx.y);
      float brx=fminf(ghx,bx.z), bry=fminf(ghy,bx.w);
      float iw=brx-tlx, ih=bry-tly;
      ovl = (iw>0.f)&&(ih>0.f);
      if (ovl | geo){
        float area = p.carea[base+pos];
        float inter = fmaxf(iw,0.f)*fmaxf(ih,0.f);
        v = inter/(ga + area - inter + 1e-12f);
        if (geo) cst = p.cpcc[base+pos] + 3.f*(-logf(v+1e-8f));
      }
    }
    unsigned long long m1 = __ballot(ovl);
    if (m1){
      int ldr = (int)(__ffsll(m1)-1);
      int off;
      if (lane == ldr) off = atomicAdd(&s_pcnt, __popcll(m1));
      off = __shfl(off, ldr);
      if (ovl) s_pos[off + __popcll(m1 & lmlt)] = v;
    }
    unsigned long long m2 = __ballot(geo);
    if (m2){
      int ldr = (int)(__ffsll(m2)-1);
      int off;
      if (lane == ldr) off = atomicAdd(&s_gcnt, __popcll(m2));
      off = __shfl(off, ldr);
      if (geo){
        int q = off + __popcll(m2 & lmlt);
        s_gcost[q] = cst; s_gpos[q] = pos;
      }
    }
  }
  __syncthreads();
  if (wid) return;                          // 7 waves done; wave 0 selects

  int pcnt = s_pcnt, gcnt = s_gcnt;         // gcnt <= 75 < GCAP

  // dk: top-10 positives by pop-extraction over s_pos (values only;
  // descending add order == jnp top_k sum order; zeros add exactly 0)
  float lmax = -1.f;
  for (int i = lane; i < pcnt; i += 64) lmax = fmaxf(lmax, s_pos[i]);
  float sum = 0.f;
  for (int k = 0; k < 10; ++k){
    float gv = lmax;
#pragma unroll
    for (int off=32; off; off>>=1) gv = fmaxf(gv, __shfl_xor(gv, off));
    if (gv <= 0.f) break;
    sum += gv;
    unsigned long long ms = __ballot(lmax == gv);
    if ((int)(__ffsll(ms)-1) == lane){      // unique owner: remove 1 instance
      bool fnd = false; float nl = -1.f;
      for (int i = lane; i < pcnt; i += 64){
        float vv = s_pos[i];
        if (!fnd && vv == gv){ fnd = true; vv = -1.f; s_pos[i] = vv; }
        nl = fmaxf(nl, vv);
      }
      lmax = nl;
    }
  }
  int dk = (int)sum; if (dk<1) dk=1; if (dk>10) dk=10;

  // selection among geo (<=2 entries/lane; all geo < all non-geo cost)
  float c0=3.0e38f, c1=3.0e38f; int p0=0x7fffffff, p1=0x7fffffff;
  if (lane < gcnt){ c0 = s_gcost[lane]; p0 = s_gpos[lane]; }
  if (lane+64 < gcnt){ c1 = s_gcost[lane+64]; p1 = s_gpos[lane+64]; }
  if (c1 < c0 || (c1==c0 && p1<p0)){
    float tc=c0; c0=c1; c1=tc; int tp=p0; p0=p1; p1=tp;
  }
  int mysel = -1, take = 0;
  for (int k = 0; k < dk; ++k){
    float gv=c0; int gi=p0;
#pragma unroll
    for (int off=32; off; off>>=1){
      float ov=__shfl_xor(gv,off); int oi=__shfl_xor(gi,off);
      if (ov<gv || (ov==gv && oi<gi)){ gv=ov; gi=oi; }
    }
    if (gv >= 2.9e38f) break;               // geo exhausted
    if (lane == k) mysel = gi;
    take++;
    if (c0==gv && p0==gi){ c0=c1; p0=p1; c1=3.0e38f; p1=0x7fffffff; }
  }

  // rare fallback: need (dk-take) non-geo picks; exact k-th smallest via
  // repeated rescan excluding previous picks by strict lex >
  float lastc = -3.0e38f; int lastp = -1;
  for (int k = take; k < dk; ++k){
    float bc = 3.0e38f; int bp = 0x7fffffff;
    int n64 = (nfg + 63) >> 6;
    for (int it = 0; it < n64; ++it){
      int pos = (it<<6) + lane;
      if (pos < nfg){
        uint32_t u = p.cpk[base+pos];
        float xc = (float)(u & 1023u), yc = (float)((u>>10)&1023u);
        float r  = (float)(20u << (u>>20));
        bool inb = (xc>glx)&&(xc<ghx)&&(yc>gly)&&(yc<ghy);
        bool geo2 = inb && (fabsf(xc-gcx)<r) && (fabsf(yc-gcy)<r);
        if (!geo2){
          float4 bx = p.cbox[base+pos];
          float tlx=fmaxf(glx,bx.x), tly=fmaxf(gly,bx.y);
          float brx=fminf(ghx,bx.z), bry=fminf(ghy,bx.w);
          float iw=fmaxf(brx-tlx,0.f), ih=fmaxf(bry-tly,0.f);
          float inter=iw*ih;
          float area = p.carea[base+pos];
          float v = inter/(ga + area - inter + 1e-12f);
          float cst = p.cpcc[base+pos] + 3.f*(-logf(v+1e-8f)) + 100000.f;
          bool gt = (cst > lastc) || (cst == lastc && pos > lastp);
          bool lt = (cst < bc)   || (cst == bc   && pos < bp);
          if (gt && lt){ bc = cst; bp = pos; }
        }
      }
    }
#pragma unroll
    for (int off=32; off; off>>=1){
      float ov=__shfl_xor(bc,off); int oi=__shfl_xor(bp,off);
      if (ov<bc || (ov==bc && oi<bp)){ bc=ov; bp=oi; }
    }
    if (bc >= 2.9e38f) break;               // candidates exhausted
    if (lane == k) mysel = bp;
    lastc = bc; lastp = bp;
  }

  if (mysel >= 0){                          // lanes 0..dk-1 hold selections
    int pos = mysel;
    float4 bx = p.cbox[base+pos];
    float area = p.carea[base+pos];
    int a = adecode(p.cpk[base+pos]);
    float tlx=fmaxf(glx,bx.x), tly=fmaxf(gly,bx.y);
    float brx=fminf(ghx,bx.z), bry=fminf(ghy,bx.w);
    float iw=fmaxf(brx-tlx,0.f), ih=fmaxf(bry-tly,0.f);
    float inter=iw*ih;
    float iou=inter/(ga + area - inter + 1e-12f);
    atomicAdd(&p.cnt[base+a], 1);
    p.miou[base+a] = iou;                   // races only when cnt>1; kCD recomputes
  }
}

// ---- kCD: conflict resolution + masked BCE + fused finalize ---------------
// kD fused via last-arriving-block ticket; finisher replicates kD's exact
// summation order -> bit-identical output. (passed absmax 0, r3/r4)
__global__ __launch_bounds__(TPB) void kCD(P p){
  int t = threadIdx.x;
  int idx = blockIdx.x*TPB + t;
  float bce=0.f, fgv=0.f;
  if (idx < BA){
    int cgt = p.cnt[idx];
    if (cgt > 0){
      int b = idx/AA, a = idx - b*AA;
      float4 mt = p.meta4[idx];
      float iouv;
      if (cgt == 1){ iouv = p.miou[idx]; }
      else {
        float4 bx = p.box4[idx];
        float xc,yc,r; ageom(a,xc,yc,r);
        int ng = p.gmax[b];
        float best=3.9e38f, biou=0.f;
        for (int g=0; g<ng; ++g){
          float4 gbb = p.gtb[b*GG+g], gcc = p.gtc[b*GG+g];
          float cost, iou = 0.f;
          if (gcc.w != 0.f){
            float tlx=fmaxf(gbb.x,bx.x), tly=fmaxf(gbb.y,bx.y);
            float brx=fminf(gbb.z,bx.z), bry=fminf(gbb.w,bx.w);
            float iw=fmaxf(brx-tlx,0.f), ih=fmaxf(bry-tly,0.f);
            float inter=iw*ih;
            iou = inter/(gcc.z + mt.x - inter + 1e-12f);
            bool inb=(xc>gbb.x)&&(xc<gbb.z)&&(yc>gbb.y)&&(yc<gbb.w);
            bool inc=(fabsf(xc-gcc.x)<r)&&(fabsf(yc-gcc.y)<r);
            cost = mt.y + 3.f*(-logf(iou+1e-8f)) + ((inb&&inc)?0.f:100000.f);
          } else cost = 1e9f;
          if (cost < best){ best=cost; biou=iou; }   // first-index argmin
        }
        iouv = biou;
      }
      float z = mt.w;
      float e = expf(-fabsf(z));
      float spz = fmaxf(z,0.f)+log1pf(e);
      float spn = fmaxf(-z,0.f)+log1pf(e);
      bce = iouv*spn + (1.f-iouv)*spz;
      fgv = 1.f;
    }
  }
  for (int off=32; off; off>>=1){
    bce += __shfl_xor(bce, off);
    fgv += __shfl_xor(fgv, off);
  }
  __shared__ float s_b[4], s_f[4];
  __shared__ int s_last;
  int lane = t & 63, wid = t >> 6;
  if (lane==0){ s_b[wid]=bce; s_f[wid]=fgv; }
  __syncthreads();
  if (t==0){
    p.pb[blockIdx.x] = s_b[0]+s_b[1]+s_b[2]+s_b[3];
    p.pf[blockIdx.x] = s_f[0]+s_f[1]+s_f[2]+s_f[3];
    __threadfence();                       // publish partials (device scope)
    int old = atomicAdd(p.ticket, 1);
    s_last = (old == NBLK-1) ? 1 : 0;
  }
  __syncthreads();
  if (s_last){
    __threadfence();                       // acquire all partials
    float sb=0.f, sf=0.f;
    for (int i = t; i < NBLK; i += TPB){ sb += p.pb[i]; sf += p.pf[i]; }
#pragma unroll
    for (int off=32; off; off>>=1){
      sb += __shfl_xor(sb, off);
      sf += __shfl_xor(sf, off);
    }
    __syncthreads();                       // s_b/s_f reuse fence
    if (lane==0){ s_b[wid]=sb; s_f[wid]=sf; }
    __syncthreads();
    if (t==0){
      float tb=s_b[0]+s_b[1]+s_b[2]+s_b[3];
      float tf=s_f[0]+s_f[1]+s_f[2]+s_f[3];
      p.out[0] = tb / fmaxf(tf, 1.f);
    }
  }
}

extern "C" void kernel_launch(void* const* d_in, const int* in_sizes, int n_in,
                              void* d_out, int out_size, void* d_ws, size_t ws_size,
                              hipStream_t stream) {
  P p;
  p.outs = d_in[0];
  p.labs = d_in[1];
  p.ss   = d_in[4];
  char* w = (char*)d_ws;
  p.box4  = (float4*)w; w += (size_t)BA*sizeof(float4);
  p.meta4 = (float4*)w; w += (size_t)BA*sizeof(float4);
  p.cbox  = (float4*)w; w += (size_t)BA*sizeof(float4);
  p.gtb   = (float4*)w; w += (size_t)NG*sizeof(float4);
  p.gtc   = (float4*)w; w += (size_t)NG*sizeof(float4);
  p.cpk   = (uint32_t*)w; w += (size_t)BA*sizeof(uint32_t);
  p.carea = (float*)w;  w += (size_t)BA*sizeof(float);
  p.cpcc  = (float*)w;  w += (size_t)BA*sizeof(float);
  p.miou  = (float*)w;  w += (size_t)BA*sizeof(float);
  p.cnt   = (int*)w;    w += (size_t)BA*sizeof(int);
  p.gmax  = (int*)w;    w += (size_t)BB*sizeof(int);
  p.nfg   = (int*)w;    w += (size_t)BB*sizeof(int);
  p.chunkcnt = (int*)w; w += (size_t)BB*NCH*sizeof(int);
  p.pb    = (float*)w;  w += (size_t)NBLK*sizeof(float);
  p.pf    = (float*)w;  w += (size_t)NBLK*sizeof(float);
  p.ticket= (int*)w;    w += sizeof(int);
  p.out   = (float*)d_out;

  kA<<<dim3(NCH, BB), TPB, 0, stream>>>(p);
  kE<<<dim3(NCH, BB), TPB, 0, stream>>>(p);
  kB<<<BB*GG, TKB, 0, stream>>>(p);
  kCD<<<NBLK, TPB, 0, stream>>>(p);
}

// Round 6
// 201.828 us; speedup vs baseline: 1.6663x; 1.0479x over previous
//
#include <hip/hip_runtime.h>
#include <hip/hip_bf16.h>
#include <stdint.h>

#define BB 32
#define GG 100
#define AA 8400
#define TPB 256
#define NCH 33                         // ceil(8400/256) chunks per image
#define TKB 512                        // kB block size (8 waves)
#define BA (BB*AA)
#define NG (BB*GG)
#define NBLK (BA/TPB)                  // 1050 kCD blocks
#define PCAP 8416                      // positives cap (>= AA, cannot overflow)
#define GCAP 128                       // geo cap (provably <= 75 per gt)

typedef __hip_bfloat16 bf16;

struct P {
  const void *outs, *labs, *ss;
  float4 *box4, *meta4, *gtb, *gtc;   // per-anchor box/meta; per-gt box/center
  float4 *cbox;                       // per-image compacted fg pred boxes
  uint32_t *cpk;                      // compacted packed (xc,yc,lvl)
  float *carea, *cpcc;                // compacted pred area / cls-cost
  float *miou, *pb, *pf;              // per-block BCE / fg partials
  int *cnt, *gmax, *nfg, *chunkcnt;
  float *out;
};

// runtime input-dtype detection: strides[0]==8.0
// f32 word 0x41000000 ; bf16 pair (8.0,8.0) 0x41004100
__device__ __forceinline__ int dtypeFlag(const void* ss){
  return (((const uint32_t*)ss)[0] == 0x41000000u) ? 1 : 0;
}
__device__ __forceinline__ float ld(const void* p, int i, int isf32){
  return isf32 ? ((const float*)p)[i] : __bfloat162float(((const bf16*)p)[i]);
}
// analytic anchor geometry (exact: ints + pow2 strides exact in f32/bf16)
__device__ __forceinline__ void ageom(int a, float& xc, float& yc, float& r){
  int x, y, s;
  if (a < 6400){ x = a % 80; y = a / 80; s = 8; }
  else if (a < 8000){ int q = a - 6400; x = q % 40; y = q / 40; s = 16; }
  else { int q = a - 8000; x = q % 20; y = q / 20; s = 32; }
  float fs = (float)s;
  xc = ((float)x + 0.5f) * fs;
  yc = ((float)y + 0.5f) * fs;
  r  = 2.5f * fs;
}
// pack integer center + level: xc(10) | yc(10)<<10 | lvl<<20
__device__ __forceinline__ uint32_t apack2(int a){
  int x, y, s, lvl;
  if (a < 6400){ x = a % 80; y = a / 80; s = 8; lvl = 0; }
  else if (a < 8000){ int q = a - 6400; x = q % 40; y = q / 40; s = 16; lvl = 1; }
  else { int q = a - 8000; x = q % 20; y = q / 20; s = 32; lvl = 2; }
  return (uint32_t)(x*s + s/2) | ((uint32_t)(y*s + s/2) << 10) | ((uint32_t)lvl << 20);
}
// exact inverse: packed -> anchor id
__device__ __forceinline__ int adecode(uint32_t u){
  int xi = u & 1023, yi = (u >> 10) & 1023, lvl = (int)(u >> 20);
  int sh = 3 + lvl, hf = 4 << lvl;
  int ax = (xi - hf) >> sh, ay = (yi - hf) >> sh;
  if (lvl == 0) return ay*80 + ax;
  if (lvl == 1) return 6400 + ay*40 + ax;
  return 8000 + ay*20 + ax;
}

// ---- kA: gt structs (self-computed) + per-anchor staging + fg + chunk count
__global__ __launch_bounds__(TPB) void kA(P p){
  __shared__ float4 s_gtb[GG], s_gtc[GG];
  __shared__ float s_o[TPB*6];
  __shared__ int s_w[4];
  __shared__ int s_ng;
  int t = threadIdx.x;
  int c = blockIdx.x, b = blockIdx.y;
  int isf = dtypeFlag(p.ss);
  if (t == 0) s_ng = 0;
  int nel = min(TPB*6, AA*6 - c*(TPB*6));      // floats in this chunk
  if (isf){
    const float4* src = (const float4*)((const float*)p.outs + (size_t)b*AA*6 + (size_t)c*(TPB*6));
    float4* dst = (float4*)s_o;
    for (int i = t; i < nel/4; i += TPB) dst[i] = src[i];
  } else {
    const uint4* src = (const uint4*)((const bf16*)p.outs + (size_t)b*AA*6 + (size_t)c*(TPB*6));
    for (int i = t; i < nel/8; i += TPB){
      uint4 u = src[i];
      int o = i*8;
      s_o[o+0]=__uint_as_float(u.x<<16); s_o[o+1]=__uint_as_float(u.x&0xffff0000u);
      s_o[o+2]=__uint_as_float(u.y<<16); s_o[o+3]=__uint_as_float(u.y&0xffff0000u);
      s_o[o+4]=__uint_as_float(u.z<<16); s_o[o+5]=__uint_as_float(u.z&0xffff0000u);
      s_o[o+6]=__uint_as_float(u.w<<16); s_o[o+7]=__uint_as_float(u.w&0xffff0000u);
    }
  }
  __syncthreads();
  if (t < GG){
    int i = b*GG + t;
    float l0 = ld(p.labs, i*5  , isf);
    float gcx= ld(p.labs, i*5+1, isf);
    float gcy= ld(p.labs, i*5+2, isf);
    float gw = ld(p.labs, i*5+3, isf);
    float gh = ld(p.labs, i*5+4, isf);
    int valid = (l0+gcx+gcy+gw+gh) > 0.f;
    float4 vb = make_float4(gcx-gw*0.5f, gcy-gh*0.5f, gcx+gw*0.5f, gcy+gh*0.5f);
    float4 vc = make_float4(gcx, gcy, gw*gh, valid ? 1.f : 0.f);
    s_gtb[t] = vb; s_gtc[t] = vc;
    if (c == 0){ p.gtb[i] = vb; p.gtc[i] = vc; }
    if (valid) atomicMax(&s_ng, t+1);
  }
  __syncthreads();
  int ng = s_ng;
  if (c == 0 && t == 0) p.gmax[b] = ng;
  int a = c*TPB + t;
  int fg = 0;
  if (a < AA){
    float cx=s_o[t*6], cy=s_o[t*6+1], w=s_o[t*6+2], h=s_o[t*6+3], ob=s_o[t*6+4], cl=s_o[t*6+5];
    int idx = b*AA + a;
    p.box4[idx] = make_float4(cx-w*0.5f, cy-h*0.5f, cx+w*0.5f, cy+h*0.5f);
    float so = 1.f/(1.f+expf(-ob));
    float sc = 1.f/(1.f+expf(-cl));
    float pcc = -logf(sqrtf(sc*so) + 1e-9f);
    float xc, yc, r; ageom(a, xc, yc, r);
    for (int g = 0; g < ng; ++g){
      float4 gb = s_gtb[g], gc = s_gtc[g];
      bool inb = (xc>gb.x)&&(xc<gb.z)&&(yc>gb.y)&&(yc<gb.w);
      bool inc = (fabsf(xc-gc.x)<r)&&(fabsf(yc-gc.y)<r);
      fg |= (gc.w != 0.f) && (inb||inc);
    }
    p.meta4[idx] = make_float4(w*h, pcc, fg ? 1.f : 0.f, cl);
    p.cnt[idx] = 0;
  }
  int lane = t & 63, wid = t >> 6;
  unsigned long long m = __ballot(fg);
  if (lane == 0) s_w[wid] = __popcll(m);
  __syncthreads();
  if (t == 0) p.chunkcnt[b*NCH + c] = s_w[0]+s_w[1]+s_w[2]+s_w[3];
}

// ---- kE: parallel order-preserving fg compaction (one block per chunk) -----
__global__ __launch_bounds__(TPB) void kE(P p){
  __shared__ int s_off;
  __shared__ int s_w[4];
  int t = threadIdx.x, c = blockIdx.x, b = blockIdx.y;
  int lane = t & 63, wid = t >> 6;
  if (wid == 0){
    int v = (lane < c) ? p.chunkcnt[b*NCH + lane] : 0;   // c <= 32 < 64 lanes
#pragma unroll
    for (int off=32; off; off>>=1) v += __shfl_xor(v, off);
    if (lane == 0) s_off = v;
  }
  int a = c*TPB + t;
  float4 mt = make_float4(0,0,0,0);
  int fg = 0;
  if (a < AA){ mt = p.meta4[b*AA+a]; fg = (mt.z != 0.f) ? 1 : 0; }
  unsigned long long m = __ballot(fg);
  int rank = __popcll(m & ((1ull<<lane)-1ull));
  if (lane == 0) s_w[wid] = __popcll(m);
  __syncthreads();
  int off = s_off;
  for (int w2 = 0; w2 < wid; ++w2) off += s_w[w2];
  if (fg){
    int pos = off + rank;
    p.cbox [b*AA+pos] = p.box4[b*AA+a];
    p.cpk  [b*AA+pos] = apack2(a);
    p.carea[b*AA+pos] = mt.x;
    p.cpcc [b*AA+pos] = mt.y;
  }
  if (c == NCH-1 && t == 0)
    p.nfg[b] = s_off + s_w[0]+s_w[1]+s_w[2]+s_w[3];
}

// ---- kB: per-(b,g) dyn_k + selection -------------------------------------
// v6 (unchanged from r5, passed absmax 0, out of top-5): COMPACT-THEN-SELECT.
// Lean ~30-op screen per pair; wave-aggregated push of survivors (positives /
// geo) into small LDS lists; wave 0 selects from ~300 / <=75 entries.
// Exactness: fp expressions verbatim from v0; top-10 sum over positives ==
// top-10 sum (x+0 exact); geo cost < 100000 <= non-geo cost (strict
// separation); rare gcnt<dk covered by exact k-th-smallest rescan.
__global__ __launch_bounds__(TKB) void kB(P p){
  __shared__ float s_pos[PCAP];
  __shared__ float s_gcost[GCAP];
  __shared__ int   s_gpos[GCAP];
  __shared__ int   s_pcnt, s_gcnt;
  int t = threadIdx.x;
  int lane = t & 63, wid = t >> 6;
  int item = blockIdx.x;
  int b = item / GG, g = item - b*GG;       // balanced across XCDs
  if (t == 0){ s_pcnt = 0; s_gcnt = 0; }
  float4 gc = p.gtc[b*GG+g];
  if (gc.w == 0.f) return;                  // uniform exit, pre-barrier
  float4 gb = p.gtb[b*GG+g];
  float glx=gb.x, gly=gb.y, ghx=gb.z, ghy=gb.w, gcx=gc.x, gcy=gc.y, ga=gc.z;
  int base = b*AA;
  int nfg = p.nfg[b];
  unsigned long long lmlt = (1ull<<lane) - 1ull;
  __syncthreads();                          // s_pcnt/s_gcnt init visible

  // main screen: ~30 VALU/pair, 20B/pair steady; heavy math only on hits
  int nIt = (nfg + TKB - 1) / TKB;
  for (int it = 0; it < nIt; ++it){
    int pos = it*TKB + t;
    bool vld = pos < nfg;
    bool ovl = false, geo = false;
    float v = 0.f, cst = 0.f;
    if (vld){
      uint32_t u = p.cpk[base+pos];
      float xc = (float)(u & 1023u), yc = (float)((u>>10)&1023u);
      float r  = (float)(20u << (u>>20));
      bool inb = (xc>glx)&&(xc<ghx)&&(yc>gly)&&(yc<ghy);
      geo = inb && (fabsf(xc-gcx)<r) && (fabsf(yc-gcy)<r);
      float4 bx = p.cbox[base+pos];
      float tlx=fmaxf(glx,bx.x), tly=fmaxf(gly,bx.y);
      float brx=fminf(ghx,bx.z), bry=fminf(ghy,bx.w);
      float iw=brx-tlx, ih=bry-tly;
      ovl = (iw>0.f)&&(ih>0.f);
      if (ovl | geo){
        float area = p.carea[base+pos];
        float inter = fmaxf(iw,0.f)*fmaxf(ih,0.f);
        v = inter/(ga + area - inter + 1e-12f);
        if (geo) cst = p.cpcc[base+pos] + 3.f*(-logf(v+1e-8f));
      }
    }
    unsigned long long m1 = __ballot(ovl);
    if (m1){
      int ldr = (int)(__ffsll(m1)-1);
      int off;
      if (lane == ldr) off = atomicAdd(&s_pcnt, __popcll(m1));
      off = __shfl(off, ldr);
      if (ovl) s_pos[off + __popcll(m1 & lmlt)] = v;
    }
    unsigned long long m2 = __ballot(geo);
    if (m2){
      int ldr = (int)(__ffsll(m2)-1);
      int off;
      if (lane == ldr) off = atomicAdd(&s_gcnt, __popcll(m2));
      off = __shfl(off, ldr);
      if (geo){
        int q = off + __popcll(m2 & lmlt);
        s_gcost[q] = cst; s_gpos[q] = pos;
      }
    }
  }
  __syncthreads();
  if (wid) return;                          // 7 waves done; wave 0 selects

  int pcnt = s_pcnt, gcnt = s_gcnt;         // gcnt <= 75 < GCAP

  // dk: top-10 positives by pop-extraction over s_pos (values only;
  // descending add order == jnp top_k sum order; zeros add exactly 0)
  float lmax = -1.f;
  for (int i = lane; i < pcnt; i += 64) lmax = fmaxf(lmax, s_pos[i]);
  float sum = 0.f;
  for (int k = 0; k < 10; ++k){
    float gv = lmax;
#pragma unroll
    for (int off=32; off; off>>=1) gv = fmaxf(gv, __shfl_xor(gv, off));
    if (gv <= 0.f) break;
    sum += gv;
    unsigned long long ms = __ballot(lmax == gv);
    if ((int)(__ffsll(ms)-1) == lane){      // unique owner: remove 1 instance
      bool fnd = false; float nl = -1.f;
      for (int i = lane; i < pcnt; i += 64){
        float vv = s_pos[i];
        if (!fnd && vv == gv){ fnd = true; vv = -1.f; s_pos[i] = vv; }
        nl = fmaxf(nl, vv);
      }
      lmax = nl;
    }
  }
  int dk = (int)sum; if (dk<1) dk=1; if (dk>10) dk=10;

  // selection among geo (<=2 entries/lane; all geo < all non-geo cost)
  float c0=3.0e38f, c1=3.0e38f; int p0=0x7fffffff, p1=0x7fffffff;
  if (lane < gcnt){ c0 = s_gcost[lane]; p0 = s_gpos[lane]; }
  if (lane+64 < gcnt){ c1 = s_gcost[lane+64]; p1 = s_gpos[lane+64]; }
  if (c1 < c0 || (c1==c0 && p1<p0)){
    float tc=c0; c0=c1; c1=tc; int tp=p0; p0=p1; p1=tp;
  }
  int mysel = -1, take = 0;
  for (int k = 0; k < dk; ++k){
    float gv=c0; int gi=p0;
#pragma unroll
    for (int off=32; off; off>>=1){
      float ov=__shfl_xor(gv,off); int oi=__shfl_xor(gi,off);
      if (ov<gv || (ov==gv && oi<gi)){ gv=ov; gi=oi; }
    }
    if (gv >= 2.9e38f) break;               // geo exhausted
    if (lane == k) mysel = gi;
    take++;
    if (c0==gv && p0==gi){ c0=c1; p0=p1; c1=3.0e38f; p1=0x7fffffff; }
  }

  // rare fallback: need (dk-take) non-geo picks; exact k-th smallest via
  // repeated rescan excluding previous picks by strict lex >
  float lastc = -3.0e38f; int lastp = -1;
  for (int k = take; k < dk; ++k){
    float bc = 3.0e38f; int bp = 0x7fffffff;
    int n64 = (nfg + 63) >> 6;
    for (int it = 0; it < n64; ++it){
      int pos = (it<<6) + lane;
      if (pos < nfg){
        uint32_t u = p.cpk[base+pos];
        float xc = (float)(u & 1023u), yc = (float)((u>>10)&1023u);
        float r  = (float)(20u << (u>>20));
        bool inb = (xc>glx)&&(xc<ghx)&&(yc>gly)&&(yc<ghy);
        bool geo2 = inb && (fabsf(xc-gcx)<r) && (fabsf(yc-gcy)<r);
        if (!geo2){
          float4 bx = p.cbox[base+pos];
          float tlx=fmaxf(glx,bx.x), tly=fmaxf(gly,bx.y);
          float brx=fminf(ghx,bx.z), bry=fminf(ghy,bx.w);
          float iw=fmaxf(brx-tlx,0.f), ih=fmaxf(bry-tly,0.f);
          float inter=iw*ih;
          float area = p.carea[base+pos];
          float v = inter/(ga + area - inter + 1e-12f);
          float cst = p.cpcc[base+pos] + 3.f*(-logf(v+1e-8f)) + 100000.f;
          bool gt = (cst > lastc) || (cst == lastc && pos > lastp);
          bool lt = (cst < bc)   || (cst == bc   && pos < bp);
          if (gt && lt){ bc = cst; bp = pos; }
        }
      }
    }
#pragma unroll
    for (int off=32; off; off>>=1){
      float ov=__shfl_xor(bc,off); int oi=__shfl_xor(bp,off);
      if (ov<bc || (ov==bc && oi<bp)){ bc=ov; bp=oi; }
    }
    if (bc >= 2.9e38f) break;               // candidates exhausted
    if (lane == k) mysel = bp;
    lastc = bc; lastp = bp;
  }

  if (mysel >= 0){                          // lanes 0..dk-1 hold selections
    int pos = mysel;
    float4 bx = p.cbox[base+pos];
    float area = p.carea[base+pos];
    int a = adecode(p.cpk[base+pos]);
    float tlx=fmaxf(glx,bx.x), tly=fmaxf(gly,bx.y);
    float brx=fminf(ghx,bx.z), bry=fminf(ghy,bx.w);
    float iw=fmaxf(brx-tlx,0.f), ih=fmaxf(bry-tly,0.f);
    float inter=iw*ih;
    float iou=inter/(ga + area - inter + 1e-12f);
    atomicAdd(&p.cnt[base+a], 1);
    p.miou[base+a] = iou;                   // races only when cnt>1; kCD recomputes
  }
}

// ---- kCD: conflict resolution + masked BCE -> per-block partials -----------
// v7: ticket fusion REVERTED (r5 post-mortem: per-block __threadfence() on
// non-coherent XCD L2s = 1050 serialized L2 writebacks + same-line device
// atomics -> 79us for a 1.3MB kernel). Kernel boundary is the cheap
// device-scope flush (one, implicit); separate kD restored (r0-proven).
__global__ __launch_bounds__(TPB) void kCD(P p){
  int t = threadIdx.x;
  int idx = blockIdx.x*TPB + t;
  float bce=0.f, fgv=0.f;
  if (idx < BA){
    int cgt = p.cnt[idx];
    if (cgt > 0){
      int b = idx/AA, a = idx - b*AA;
      float4 mt = p.meta4[idx];
      float iouv;
      if (cgt == 1){ iouv = p.miou[idx]; }
      else {
        float4 bx = p.box4[idx];
        float xc,yc,r; ageom(a,xc,yc,r);
        int ng = p.gmax[b];
        float best=3.9e38f, biou=0.f;
        for (int g=0; g<ng; ++g){
          float4 gbb = p.gtb[b*GG+g], gcc = p.gtc[b*GG+g];
          float cost, iou = 0.f;
          if (gcc.w != 0.f){
            float tlx=fmaxf(gbb.x,bx.x), tly=fmaxf(gbb.y,bx.y);
            float brx=fminf(gbb.z,bx.z), bry=fminf(gbb.w,bx.w);
            float iw=fmaxf(brx-tlx,0.f), ih=fmaxf(bry-tly,0.f);
            float inter=iw*ih;
            iou = inter/(gcc.z + mt.x - inter + 1e-12f);
            bool inb=(xc>gbb.x)&&(xc<gbb.z)&&(yc>gbb.y)&&(yc<gbb.w);
            bool inc=(fabsf(xc-gcc.x)<r)&&(fabsf(yc-gcc.y)<r);
            cost = mt.y + 3.f*(-logf(iou+1e-8f)) + ((inb&&inc)?0.f:100000.f);
          } else cost = 1e9f;
          if (cost < best){ best=cost; biou=iou; }   // first-index argmin
        }
        iouv = biou;
      }
      float z = mt.w;
      float e = expf(-fabsf(z));
      float spz = fmaxf(z,0.f)+log1pf(e);
      float spn = fmaxf(-z,0.f)+log1pf(e);
      bce = iouv*spn + (1.f-iouv)*spz;
      fgv = 1.f;
    }
  }
  for (int off=32; off; off>>=1){
    bce += __shfl_xor(bce, off);
    fgv += __shfl_xor(fgv, off);
  }
  __shared__ float s_b[4], s_f[4];
  int lane = t & 63, wid = t >> 6;
  if (lane==0){ s_b[wid]=bce; s_f[wid]=fgv; }
  __syncthreads();
  if (t==0){
    // disjoint per-block partials: no atomics, no fences, no hot cache line
    p.pb[blockIdx.x] = s_b[0]+s_b[1]+s_b[2]+s_b[3];
    p.pf[blockIdx.x] = s_f[0]+s_f[1]+s_f[2]+s_f[3];
  }
}

// ---- kD: reduce 1050 partials + finalize (1 block) -------------------------
__global__ __launch_bounds__(TPB) void kD(P p){
  int t = threadIdx.x;
  float sb=0.f, sf=0.f;
  for (int i = t; i < NBLK; i += TPB){ sb += p.pb[i]; sf += p.pf[i]; }
#pragma unroll
  for (int off=32; off; off>>=1){
    sb += __shfl_xor(sb, off);
    sf += __shfl_xor(sf, off);
  }
  __shared__ float s_b[4], s_f[4];
  int lane = t & 63, wid = t >> 6;
  if (lane==0){ s_b[wid]=sb; s_f[wid]=sf; }
  __syncthreads();
  if (t==0){
    float tb=s_b[0]+s_b[1]+s_b[2]+s_b[3];
    float tf=s_f[0]+s_f[1]+s_f[2]+s_f[3];
    p.out[0] = tb / fmaxf(tf, 1.f);
  }
}

extern "C" void kernel_launch(void* const* d_in, const int* in_sizes, int n_in,
                              void* d_out, int out_size, void* d_ws, size_t ws_size,
                              hipStream_t stream) {
  P p;
  p.outs = d_in[0];
  p.labs = d_in[1];
  p.ss   = d_in[4];
  char* w = (char*)d_ws;
  p.box4  = (float4*)w; w += (size_t)BA*sizeof(float4);
  p.meta4 = (float4*)w; w += (size_t)BA*sizeof(float4);
  p.cbox  = (float4*)w; w += (size_t)BA*sizeof(float4);
  p.gtb   = (float4*)w; w += (size_t)NG*sizeof(float4);
  p.gtc   = (float4*)w; w += (size_t)NG*sizeof(float4);
  p.cpk   = (uint32_t*)w; w += (size_t)BA*sizeof(uint32_t);
  p.carea = (float*)w;  w += (size_t)BA*sizeof(float);
  p.cpcc  = (float*)w;  w += (size_t)BA*sizeof(float);
  p.miou  = (float*)w;  w += (size_t)BA*sizeof(float);
  p.cnt   = (int*)w;    w += (size_t)BA*sizeof(int);
  p.gmax  = (int*)w;    w += (size_t)BB*sizeof(int);
  p.nfg   = (int*)w;    w += (size_t)BB*sizeof(int);
  p.chunkcnt = (int*)w; w += (size_t)BB*NCH*sizeof(int);
  p.pb    = (float*)w;  w += (size_t)NBLK*sizeof(float);
  p.pf    = (float*)w;  w += (size_t)NBLK*sizeof(float);
  p.out   = (float*)d_out;

  kA<<<dim3(NCH, BB), TPB, 0, stream>>>(p);
  kE<<<dim3(NCH, BB), TPB, 0, stream>>>(p);
  kB<<<BB*GG, TKB, 0, stream>>>(p);
  kCD<<<NBLK, TPB, 0, stream>>>(p);
  kD<<<1, TPB, 0, stream>>>(p);
}